// Round 9
// baseline (565.785 us; speedup 1.0000x reference)
//
#include <hip/hip_runtime.h>

typedef __bf16 bf16;
typedef __attribute__((ext_vector_type(4))) __bf16 bf16x4;
typedef __attribute__((ext_vector_type(8))) __bf16 bf16x8;
typedef __attribute__((ext_vector_type(4))) float f32x4;

#define MFMA16(a, b, c) __builtin_amdgcn_mfma_f32_16x16x32_bf16((a), (b), (c), 0, 0, 0)

constexpr int N   = 8192;
constexpr int HID = 64;

// async global->LDS, 16B per lane; LDS dest = wave-uniform base + lane*16
__device__ __forceinline__ void gload16(const void* g, void* l) {
  __builtin_amdgcn_global_load_lds((const __attribute__((address_space(1))) char*)g,
                                   (__attribute__((address_space(3))) char*)l, 16, 0, 0);
}

// One 16-row M-tile, full K, no partials. C[16][64] = A[16][K](f32) @ Bt[64][K]^T(bf16).
// 2-phase pipeline: stage tile t+1 (global_load_lds) before computing tile t.
// EPI 0: out = C^T bf16            (s1 -> S1T)
// EPI 1: out = relu(C)^T bf16      (h1 -> h1T)
// EPI 2: mu = C@W2, lv = C@W3      (second MFMA vs staged W23T)
template <int EPI>
__global__ __launch_bounds__(256) void gcn_pass(const float* __restrict__ A, int K,
                                                const bf16* __restrict__ Bt,
                                                bf16* __restrict__ outT,
                                                const bf16* __restrict__ W23T,
                                                float* __restrict__ mu,
                                                float* __restrict__ lv) {
  __shared__ float Af[2][16 * 64];          // A tile f32, linear (gload dest)
  __shared__ bf16  Bf[2][64 * 64];          // B tile bf16, linear (gload dest)
  __shared__ float Ht[16][72];              // epilogue tile (72: 16B-aligned rows)
  __shared__ bf16  Wl[EPI == 2 ? 128 * 64 : 8];
  const int tid = threadIdx.x, lane = tid & 63, w = tid >> 6;
  const int i0 = blockIdx.x * 16;
  const int nt = K / 64;

  if constexpr (EPI == 2) {  // stage W23T [128][64] bf16 = 16KB once
#pragma unroll
    for (int s = 0; s < 4; ++s) {
      const int idx = tid + s * 256;
      reinterpret_cast<bf16x8*>(Wl)[idx] = reinterpret_cast<const bf16x8*>(W23T)[idx];
    }
  }

  auto stage = [&](int b, int t) {
    const int k0 = t * 64;
    {  // A: wave w stages rows 4w..4w+3 (1KB)
      const int r = 4 * w + (lane >> 4), u = lane & 15;
      gload16(&A[(size_t)(i0 + r) * K + k0 + u * 4], &Af[b][w * 256]);
    }
#pragma unroll
    for (int j = 0; j < 2; ++j) {  // B: wave w stages chunks 2w,2w+1 (8 rows each)
      const int c = 2 * w + j;
      const int r = 8 * c + (lane >> 3), u = lane & 7;
      gload16(&Bt[(size_t)r * K + k0 + u * 8], &Bf[b][c * 512]);
    }
  };

  stage(0, 0);
  f32x4 acc = {0.f, 0.f, 0.f, 0.f};
  int buf = 0;
  for (int t = 0; t < nt; ++t) {
    __syncthreads();                         // stage(t) landed; prior reads done
    if (t + 1 < nt) stage(buf ^ 1, t + 1);   // prefetch under compute
#pragma unroll
    for (int kk = 0; kk < 2; ++kk) {
      const int ao = (lane & 15) * 64 + kk * 32 + (lane >> 4) * 8;
      const float4 a0 = *reinterpret_cast<const float4*>(&Af[buf][ao]);
      const float4 a1 = *reinterpret_cast<const float4*>(&Af[buf][ao + 4]);
      bf16x8 fa;
      fa[0] = (bf16)a0.x; fa[1] = (bf16)a0.y; fa[2] = (bf16)a0.z; fa[3] = (bf16)a0.w;
      fa[4] = (bf16)a1.x; fa[5] = (bf16)a1.y; fa[6] = (bf16)a1.z; fa[7] = (bf16)a1.w;
      const bf16x8 fb = *reinterpret_cast<const bf16x8*>(
          &Bf[buf][(w * 16 + (lane & 15)) * 64 + kk * 32 + (lane >> 4) * 8]);
      acc = MFMA16(fa, fb, acc);
    }
    buf ^= 1;
  }

  // ---- epilogue ----
  // C/D layout (m89-verified): col = lane&15, row = (lane>>4)*4 + r
  {
    const int col = w * 16 + (lane & 15), r4 = (lane >> 4) * 4;
    __syncthreads();
#pragma unroll
    for (int r = 0; r < 4; ++r)
      Ht[r4 + r][col] = (EPI == 1) ? fmaxf(acc[r], 0.f) : acc[r];
    __syncthreads();
  }
  if constexpr (EPI <= 1) {
    // transpose-store: outT[j][i0..i0+16] bf16
    const int j = tid >> 2, iq = tid & 3;
    bf16x4 o;
#pragma unroll
    for (int e = 0; e < 4; ++e) o[e] = (bf16)Ht[iq * 4 + e][j];
    *reinterpret_cast<bf16x4*>(&outT[(size_t)j * N + i0 + iq * 4]) = o;
  } else {
    // second MFMA: [16 rows][128 cols] = Ht(16x64) @ W23
    f32x4 a2[2] = {};
#pragma unroll
    for (int kk = 0; kk < 2; ++kk) {
      const int co = kk * 32 + (lane >> 4) * 8;
      const float4 t0 = *reinterpret_cast<const float4*>(&Ht[lane & 15][co]);
      const float4 t1 = *reinterpret_cast<const float4*>(&Ht[lane & 15][co + 4]);
      bf16x8 fa;
      fa[0] = (bf16)t0.x; fa[1] = (bf16)t0.y; fa[2] = (bf16)t0.z; fa[3] = (bf16)t0.w;
      fa[4] = (bf16)t1.x; fa[5] = (bf16)t1.y; fa[6] = (bf16)t1.z; fa[7] = (bf16)t1.w;
#pragma unroll
      for (int q = 0; q < 2; ++q) {
        const int nb = w * 2 + q;
        const bf16x8 fw = *reinterpret_cast<const bf16x8*>(
            &Wl[(nb * 16 + (lane & 15)) * 64 + kk * 32 + (lane >> 4) * 8]);
        a2[q] = MFMA16(fa, fw, a2[q]);
      }
    }
#pragma unroll
    for (int q = 0; q < 2; ++q) {
      const int nb = w * 2 + q;
      const int cc = nb * 16 + (lane & 15);
#pragma unroll
      for (int r = 0; r < 4; ++r) {
        const int row = i0 + (lane >> 4) * 4 + r;
        if (cc < 64) mu[(size_t)row * HID + cc] = a2[q][r];
        else         lv[(size_t)row * HID + (cc - 64)] = a2[q][r];
      }
    }
  }
}

// W1 [256][64] f32 -> W1T [64][256] bf16
__global__ void prep_w1t(const float* __restrict__ W1, bf16* __restrict__ W1T) {
  const int idx = blockIdx.x * 256 + threadIdx.x;  // 16384
  const int j = idx >> 8, k = idx & 255;
  W1T[idx] = (bf16)W1[k * HID + j];
}

// W2,W3 [64][64] f32 -> W23T [128][64] bf16  (row j: weight column j)
__global__ void prep_w23t(const float* __restrict__ W2, const float* __restrict__ W3,
                          bf16* __restrict__ Wt) {
  const int idx = blockIdx.x * 256 + threadIdx.x;  // 8192
  const int j = idx >> 6, c = idx & 63;
  Wt[idx] = (bf16)(j < 64 ? W2[c * HID + j] : W3[c * HID + (j - 64)]);
}

// recon[i][j] = dot(mu[i,:], mu[j,:]) ; K=64, write-bound
constexpr int LDT = 72;
__global__ __launch_bounds__(256) void recon_mm(const float* __restrict__ mu,
                                                float* __restrict__ out) {
  __shared__ bf16 Am[128 * LDT];
  __shared__ bf16 Bm[128 * LDT];
  const int tid = threadIdx.x, lane = tid & 63, wave = tid >> 6;
  const int i0 = blockIdx.x * 128, j0 = blockIdx.y * 128;
  {
    const int rr = tid >> 4, c4 = tid & 15;
#pragma unroll
    for (int s = 0; s < 8; ++s) {
      const int row = rr + s * 16;
      const float4 v = *reinterpret_cast<const float4*>(&mu[(size_t)(i0 + row) * HID + c4 * 4]);
      bf16x4 o;
      o[0] = (bf16)v.x; o[1] = (bf16)v.y; o[2] = (bf16)v.z; o[3] = (bf16)v.w;
      *reinterpret_cast<bf16x4*>(&Am[row * LDT + c4 * 4]) = o;
      const float4 u = *reinterpret_cast<const float4*>(&mu[(size_t)(j0 + row) * HID + c4 * 4]);
      bf16x4 p;
      p[0] = (bf16)u.x; p[1] = (bf16)u.y; p[2] = (bf16)u.z; p[3] = (bf16)u.w;
      *reinterpret_cast<bf16x4*>(&Bm[row * LDT + c4 * 4]) = p;
    }
  }
  __syncthreads();
  f32x4 acc[2][8] = {};
  const int rA = wave * 32 + (lane & 15);
#pragma unroll
  for (int kk = 0; kk < 2; ++kk) {
    const int kb = kk * 32 + ((lane >> 4) << 3);
    const bf16x8 a0 = *reinterpret_cast<const bf16x8*>(&Am[rA * LDT + kb]);
    const bf16x8 a1 = *reinterpret_cast<const bf16x8*>(&Am[(rA + 16) * LDT + kb]);
#pragma unroll
    for (int n = 0; n < 8; ++n) {
      const bf16x8 b = *reinterpret_cast<const bf16x8*>(&Bm[(n * 16 + (lane & 15)) * LDT + kb]);
      acc[0][n] = MFMA16(a0, b, acc[0][n]);
      acc[1][n] = MFMA16(a1, b, acc[1][n]);
    }
  }
  const int r4 = (lane >> 4) << 2, c = lane & 15;
#pragma unroll
  for (int m = 0; m < 2; ++m)
#pragma unroll
    for (int n = 0; n < 8; ++n)
#pragma unroll
      for (int r = 0; r < 4; ++r)
        out[(size_t)(i0 + wave * 32 + m * 16 + r4 + r) * N + j0 + n * 16 + c] = acc[m][n][r];
}

extern "C" void kernel_launch(void* const* d_in, const int* in_sizes, int n_in, void* d_out,
                              int out_size, void* d_ws, size_t ws_size, hipStream_t stream) {
  const float* x   = (const float*)d_in[0];
  const float* adj = (const float*)d_in[1];
  const float* W1  = (const float*)d_in[2];
  const float* W2  = (const float*)d_in[3];
  const float* W3  = (const float*)d_in[4];

  float* out    = (float*)d_out;
  float* recon  = out;                          // [8192][8192] 256 MiB
  float* mu_out = out + (size_t)N * N;          // outside recon region
  float* lv_out = mu_out + (size_t)N * HID;

  // Scratch inside recon region (first ~3 MiB); all dead before recon_mm runs.
  char* scr   = (char*)d_out;
  bf16* S1T   = (bf16*)(scr + 0);               // [64][8192]  1 MB
  bf16* h1T   = (bf16*)(scr + (1u << 20));      // [64][8192]  1 MB
  bf16* W1T   = (bf16*)(scr + (2u << 20));      // [64][256]   32 KB
  bf16* W23T  = (bf16*)(scr + (2u << 20) + 65536);  // [128][64] 16 KB

  prep_w1t<<<64, 256, 0, stream>>>(W1, W1T);
  prep_w23t<<<32, 256, 0, stream>>>(W2, W3, W23T);
  // S1T = (x @ W1)^T
  gcn_pass<0><<<512, 256, 0, stream>>>(x, 256, W1T, S1T, nullptr, nullptr, nullptr);
  // h1T = relu(adj @ s1)^T
  gcn_pass<1><<<512, 256, 0, stream>>>(adj, N, S1T, h1T, nullptr, nullptr, nullptr);
  // mu, lv = (adj @ h1) @ {W2,W3}
  gcn_pass<2><<<512, 256, 0, stream>>>(adj, N, h1T, nullptr, W23T, mu_out, lv_out);
  // recon = mu @ mu^T
  recon_mm<<<dim3(64, 64), 256, 0, stream>>>(mu_out, recon);
}

// Round 10
// 320.230 us; speedup vs baseline: 1.7668x; 1.7668x over previous
//
#include <hip/hip_runtime.h>

typedef __bf16 bf16;
typedef __attribute__((ext_vector_type(4))) __bf16 bf16x4;
typedef __attribute__((ext_vector_type(8))) __bf16 bf16x8;
typedef __attribute__((ext_vector_type(4))) float f32x4;

#define MFMA16(a, b, c) __builtin_amdgcn_mfma_f32_16x16x32_bf16((a), (b), (c), 0, 0, 0)
#define WAITV3() asm volatile("s_waitcnt vmcnt(3)" ::: "memory")
#define WAITV0() asm volatile("s_waitcnt vmcnt(0)" ::: "memory")

constexpr int N   = 8192;
constexpr int HID = 64;

// async global->LDS, 16B per lane; LDS dest = wave-uniform base + lane*16
__device__ __forceinline__ void gload16(const void* g, void* l) {
  __builtin_amdgcn_global_load_lds((const __attribute__((address_space(1))) char*)g,
                                   (__attribute__((address_space(3))) char*)l, 16, 0, 0);
}

// One 16-row M-tile, full K. C[16][64] = A[16][K](f32) @ Bt[64][K]^T(bf16).
// 3-deep pipeline with counted vmcnt(3) + raw s_barrier (loads stay in flight
// across barriers). LDS XOR-swizzled (unit ^= row&7) via inverse-swizzled
// global source (gload dest linear) + swizzled ds_read -> conflict-free.
// EPI 0: out = C^T bf16 ; EPI 1: out = relu(C)^T bf16 ; EPI 2: mu/lv = C@{W2,W3}
template <int EPI>
__global__ __launch_bounds__(256) void gcn_pass(const float* __restrict__ A, int K,
                                                const bf16* __restrict__ Bt,
                                                bf16* __restrict__ outT,
                                                const bf16* __restrict__ W23T,
                                                float* __restrict__ mu,
                                                float* __restrict__ lv) {
  __shared__ float Af[3][16 * 64];          // A tiles f32 (gload dest, linear)
  __shared__ bf16  Bf[3][64 * 64];          // B tiles bf16 (gload dest, linear)
  __shared__ float Ht[16][72];              // epilogue tile
  __shared__ bf16  Wl[EPI == 2 ? 128 * 64 : 8];
  const int tid = threadIdx.x, lane = tid & 63, w = tid >> 6;
  const int i0 = blockIdx.x * 16;
  const int nt = K / 64;

  if constexpr (EPI == 2) {  // stage W23T [128][64] bf16 = 16KB once
#pragma unroll
    for (int s = 0; s < 4; ++s) {
      const int idx = tid + s * 256;
      reinterpret_cast<bf16x8*>(Wl)[idx] = reinterpret_cast<const bf16x8*>(W23T)[idx];
    }
  }

  // per-lane fragment constants (read side)
  const int r = lane & 15, hi = lane >> 4;
  const int swz = (r & 7) << 4;                       // byte-level XOR swizzle
  const int aoff0 = ((hi * 32) ^ swz) >> 2;           // f32 units, 1st 16B
  const int aoff1 = (((hi * 32) + 16) ^ swz) >> 2;    // f32 units, 2nd 16B
  const int boff0 = ((hi * 16) ^ swz) >> 1;           // bf16 units (kk=0); kk=1: ^32

  auto stage = [&](int b, int t) {
    const int k0 = t * 64;
    {  // A: wave w stages rows 4w..4w+3 (1KB linear dest, swizzled source)
      const int R = 4 * w + (lane >> 4);
      const int u = lane & 15;
      const int so = ((u * 16) ^ ((R & 7) << 4)) >> 2;
      gload16(&A[(size_t)(i0 + R) * K + k0 + so], &Af[b][w * 256]);
    }
#pragma unroll
    for (int j = 0; j < 2; ++j) {  // B: wave w stages chunks 2w+j (8 rows, 1KB each)
      const int c = 2 * w + j;
      const int R = 8 * c + (lane >> 3);
      const int u = lane & 7;
      const int so = ((u * 16) ^ ((R & 7) << 4)) >> 1;
      gload16(&Bt[(size_t)R * K + k0 + so], &Bf[b][c * 512]);
    }
  };

  stage(0, 0);
  if (nt > 1) stage(1, 1);
  f32x4 acc = {0.f, 0.f, 0.f, 0.f};
  for (int t = 0; t < nt; ++t) {
    if (t + 1 < nt) { WAITV3(); } else { WAITV0(); }   // counted: tile t landed
    __builtin_amdgcn_s_barrier();
    __builtin_amdgcn_sched_barrier(0);
    if (t + 2 < nt) stage((t + 2) % 3, t + 2);         // prefetch stays in flight
    const float* Ab = Af[t % 3];
    const bf16*  Bb = Bf[t % 3];
#pragma unroll
    for (int kk = 0; kk < 2; ++kk) {
      const float4 a0 = *reinterpret_cast<const float4*>(&Ab[r * 64 + kk * 32 + aoff0]);
      const float4 a1 = *reinterpret_cast<const float4*>(&Ab[r * 64 + kk * 32 + aoff1]);
      bf16x8 fa;
      fa[0] = (bf16)a0.x; fa[1] = (bf16)a0.y; fa[2] = (bf16)a0.z; fa[3] = (bf16)a0.w;
      fa[4] = (bf16)a1.x; fa[5] = (bf16)a1.y; fa[6] = (bf16)a1.z; fa[7] = (bf16)a1.w;
      const bf16x8 fb = *reinterpret_cast<const bf16x8*>(
          &Bb[(w * 16 + r) * 64 + (kk ? (boff0 ^ 32) : boff0)]);
      acc = MFMA16(fa, fb, acc);
    }
  }

  // ---- epilogue ----
  // C/D layout (m89-verified): col = lane&15, row = (lane>>4)*4 + reg
  {
    const int col = w * 16 + (lane & 15), r4 = (lane >> 4) * 4;
    __syncthreads();
#pragma unroll
    for (int rr = 0; rr < 4; ++rr)
      Ht[r4 + rr][col] = (EPI == 1) ? fmaxf(acc[rr], 0.f) : acc[rr];
    __syncthreads();
  }
  if constexpr (EPI <= 1) {
    // transpose-store: outT[j][i0..i0+16] bf16
    const int j = tid >> 2, iq = tid & 3;
    bf16x4 o;
#pragma unroll
    for (int e = 0; e < 4; ++e) o[e] = (bf16)Ht[iq * 4 + e][j];
    *reinterpret_cast<bf16x4*>(&outT[(size_t)j * N + i0 + iq * 4]) = o;
  } else {
    // second MFMA: [16 rows][128 cols] = Ht(16x64) @ W23
    f32x4 a2[2] = {};
#pragma unroll
    for (int kk = 0; kk < 2; ++kk) {
      const int co = kk * 32 + hi * 8;
      const float4 t0 = *reinterpret_cast<const float4*>(&Ht[r][co]);
      const float4 t1 = *reinterpret_cast<const float4*>(&Ht[r][co + 4]);
      bf16x8 fa;
      fa[0] = (bf16)t0.x; fa[1] = (bf16)t0.y; fa[2] = (bf16)t0.z; fa[3] = (bf16)t0.w;
      fa[4] = (bf16)t1.x; fa[5] = (bf16)t1.y; fa[6] = (bf16)t1.z; fa[7] = (bf16)t1.w;
#pragma unroll
      for (int q = 0; q < 2; ++q) {
        const int nb = w * 2 + q;
        const bf16x8 fw = *reinterpret_cast<const bf16x8*>(
            &Wl[(nb * 16 + r) * 64 + kk * 32 + hi * 8]);
        a2[q] = MFMA16(fa, fw, a2[q]);
      }
    }
#pragma unroll
    for (int q = 0; q < 2; ++q) {
      const int cc = (w * 2 + q) * 16 + r;
#pragma unroll
      for (int rr = 0; rr < 4; ++rr) {
        const int row = i0 + hi * 4 + rr;
        if (cc < 64) mu[(size_t)row * HID + cc] = a2[q][rr];
        else         lv[(size_t)row * HID + (cc - 64)] = a2[q][rr];
      }
    }
  }
}

// W1 [256][64] f32 -> W1T [64][256] bf16
__global__ void prep_w1t(const float* __restrict__ W1, bf16* __restrict__ W1T) {
  const int idx = blockIdx.x * 256 + threadIdx.x;  // 16384
  const int j = idx >> 8, k = idx & 255;
  W1T[idx] = (bf16)W1[k * HID + j];
}

// W2,W3 [64][64] f32 -> W23T [128][64] bf16  (row j: weight column j)
__global__ void prep_w23t(const float* __restrict__ W2, const float* __restrict__ W3,
                          bf16* __restrict__ Wt) {
  const int idx = blockIdx.x * 256 + threadIdx.x;  // 8192
  const int j = idx >> 6, c = idx & 63;
  Wt[idx] = (bf16)(j < 64 ? W2[c * HID + j] : W3[c * HID + (j - 64)]);
}

// recon[i][j] = dot(mu[i,:], mu[j,:]) ; K=64, write-bound
constexpr int LDT = 72;
__global__ __launch_bounds__(256) void recon_mm(const float* __restrict__ mu,
                                                float* __restrict__ out) {
  __shared__ bf16 Am[128 * LDT];
  __shared__ bf16 Bm[128 * LDT];
  const int tid = threadIdx.x, lane = tid & 63, wave = tid >> 6;
  const int i0 = blockIdx.x * 128, j0 = blockIdx.y * 128;
  {
    const int rr = tid >> 4, c4 = tid & 15;
#pragma unroll
    for (int s = 0; s < 8; ++s) {
      const int row = rr + s * 16;
      const float4 v = *reinterpret_cast<const float4*>(&mu[(size_t)(i0 + row) * HID + c4 * 4]);
      bf16x4 o;
      o[0] = (bf16)v.x; o[1] = (bf16)v.y; o[2] = (bf16)v.z; o[3] = (bf16)v.w;
      *reinterpret_cast<bf16x4*>(&Am[row * LDT + c4 * 4]) = o;
      const float4 u = *reinterpret_cast<const float4*>(&mu[(size_t)(j0 + row) * HID + c4 * 4]);
      bf16x4 p;
      p[0] = (bf16)u.x; p[1] = (bf16)u.y; p[2] = (bf16)u.z; p[3] = (bf16)u.w;
      *reinterpret_cast<bf16x4*>(&Bm[row * LDT + c4 * 4]) = p;
    }
  }
  __syncthreads();
  f32x4 acc[2][8] = {};
  const int rA = wave * 32 + (lane & 15);
#pragma unroll
  for (int kk = 0; kk < 2; ++kk) {
    const int kb = kk * 32 + ((lane >> 4) << 3);
    const bf16x8 a0 = *reinterpret_cast<const bf16x8*>(&Am[rA * LDT + kb]);
    const bf16x8 a1 = *reinterpret_cast<const bf16x8*>(&Am[(rA + 16) * LDT + kb]);
#pragma unroll
    for (int n = 0; n < 8; ++n) {
      const bf16x8 b = *reinterpret_cast<const bf16x8*>(&Bm[(n * 16 + (lane & 15)) * LDT + kb]);
      acc[0][n] = MFMA16(a0, b, acc[0][n]);
      acc[1][n] = MFMA16(a1, b, acc[1][n]);
    }
  }
  const int r4 = (lane >> 4) << 2, c = lane & 15;
#pragma unroll
  for (int m = 0; m < 2; ++m)
#pragma unroll
    for (int n = 0; n < 8; ++n)
#pragma unroll
      for (int rr = 0; rr < 4; ++rr)
        out[(size_t)(i0 + wave * 32 + m * 16 + r4 + rr) * N + j0 + n * 16 + c] = acc[m][n][rr];
}

extern "C" void kernel_launch(void* const* d_in, const int* in_sizes, int n_in, void* d_out,
                              int out_size, void* d_ws, size_t ws_size, hipStream_t stream) {
  const float* x   = (const float*)d_in[0];
  const float* adj = (const float*)d_in[1];
  const float* W1  = (const float*)d_in[2];
  const float* W2  = (const float*)d_in[3];
  const float* W3  = (const float*)d_in[4];

  float* out    = (float*)d_out;
  float* recon  = out;                          // [8192][8192] 256 MiB
  float* mu_out = out + (size_t)N * N;          // outside recon region
  float* lv_out = mu_out + (size_t)N * HID;

  // Scratch inside recon region (first ~3 MiB); all dead before recon_mm runs.
  char* scr   = (char*)d_out;
  bf16* S1T   = (bf16*)(scr + 0);               // [64][8192]  1 MB
  bf16* h1T   = (bf16*)(scr + (1u << 20));      // [64][8192]  1 MB
  bf16* W1T   = (bf16*)(scr + (2u << 20));      // [64][256]   32 KB
  bf16* W23T  = (bf16*)(scr + (2u << 20) + 65536);  // [128][64] 16 KB

  prep_w1t<<<64, 256, 0, stream>>>(W1, W1T);
  prep_w23t<<<32, 256, 0, stream>>>(W2, W3, W23T);
  // S1T = (x @ W1)^T
  gcn_pass<0><<<512, 256, 0, stream>>>(x, 256, W1T, S1T, nullptr, nullptr, nullptr);
  // h1T = relu(adj @ s1)^T
  gcn_pass<1><<<512, 256, 0, stream>>>(adj, N, S1T, h1T, nullptr, nullptr, nullptr);
  // mu, lv = (adj @ h1) @ {W2,W3}
  gcn_pass<2><<<512, 256, 0, stream>>>(adj, N, h1T, nullptr, W23T, mu_out, lv_out);
  // recon = mu @ mu^T
  recon_mm<<<dim3(64, 64), 256, 0, stream>>>(mu_out, recon);
}